// Round 21
// baseline (2757.954 us; speedup 1.0000x reference)
//
#include <hip/hip_runtime.h>
#include <hip/hip_bf16.h>
#include <math.h>

#define DIM 128

typedef float v2f __attribute__((ext_vector_type(2)));
typedef _Float16 v2h __attribute__((ext_vector_type(2)));
typedef _Float16 h8v __attribute__((ext_vector_type(8)));  // 8 f16 (4 VGPR) MFMA frag
typedef short s8v __attribute__((ext_vector_type(8)));     // 8 bf16 (4 VGPR)
typedef float f4v __attribute__((ext_vector_type(4)));

// DPP move: lane i <- lane i+N (row_shl:N) or quad_perm etc. VALU-speed.
template<int CTRL>
__device__ inline float dpp_movf(float v) {
  int x = __builtin_amdgcn_update_dpp(0, __float_as_int(v), CTRL, 0xF, 0xF, true);
  return __int_as_float(x);
}
template<int CTRL>
__device__ inline float dpp_xadd(float v) { return v + dpp_movf<CTRL>(v); }

// 8-wide f16 dot, fp32 accum, operands pre-packed in uint4 (bit_cast = free)
__device__ inline float dot8u(uint4 a, uint4 b, float acc) {
#if __has_builtin(__builtin_amdgcn_fdot2)
  acc = __builtin_amdgcn_fdot2(__builtin_bit_cast(v2h, a.x), __builtin_bit_cast(v2h, b.x), acc, false);
  acc = __builtin_amdgcn_fdot2(__builtin_bit_cast(v2h, a.y), __builtin_bit_cast(v2h, b.y), acc, false);
  acc = __builtin_amdgcn_fdot2(__builtin_bit_cast(v2h, a.z), __builtin_bit_cast(v2h, b.z), acc, false);
  acc = __builtin_amdgcn_fdot2(__builtin_bit_cast(v2h, a.w), __builtin_bit_cast(v2h, b.w), acc, false);
#else
  const v2h* pa = (const v2h*)&a; const v2h* pb = (const v2h*)&b;
#pragma unroll
  for (int i = 0; i < 4; ++i) {
    acc += (float)pa[i][0] * (float)pb[i][0];
    acc += (float)pa[i][1] * (float)pb[i][1];
  }
#endif
  return acc;
}

__device__ inline unsigned pk2h(float a, float b) {
  return __builtin_bit_cast(unsigned, __builtin_amdgcn_cvt_pkrtz(a, b));
}
__device__ inline float sigm_fast(float z) {
  return __builtin_amdgcn_rcpf(1.f + __expf(-z));
}
__device__ inline float tanh_fast(float z) {
  float e = __expf(-2.f * z);
  return (1.f - e) * __builtin_amdgcn_rcpf(1.f + e);
}
// fp32 -> bf16 RNE
__device__ inline ushort f2bf(float x) {
  unsigned u = __builtin_bit_cast(unsigned, x);
  return (ushort)((u + 0x7FFFu + ((u >> 16) & 1u)) >> 16);
}
__device__ inline unsigned pk2bf(float a, float b) {
  return (unsigned)f2bf(a) | ((unsigned)f2bf(b) << 16);
}

// ---------------- gather rows from embedding table ----------------
__global__ void gather_rows(const float* __restrict__ table, const int* __restrict__ idx,
                            float* __restrict__ dst, int n) {
  int i = blockIdx.x * blockDim.x + threadIdx.x;
  int total = n * 32;
  if (i >= total) return;
  int r = i >> 5, c = i & 31;
  const float4* src = (const float4*)table + (size_t)idx[r] * 32 + c;
  ((float4*)dst)[i] = *src;
}
// gather + f16 copy (for wvb)
__global__ void gather_rows_wv(const float* __restrict__ table, const int* __restrict__ idx,
                               float* __restrict__ dst, _Float16* __restrict__ dsth, int n) {
  int i = blockIdx.x * blockDim.x + threadIdx.x;
  int total = n * 32;
  if (i >= total) return;
  int r = i >> 5, c = i & 31;
  float4 v = ((const float4*)table)[(size_t)idx[r] * 32 + c];
  ((float4*)dst)[i] = v;
  ((uint2*)dsth)[i] = make_uint2(pk2h(v.x, v.y), pk2h(v.z, v.w));
}

// ---------------- fp32 -> f16 convert ----------------
__global__ void conv_f16(const float* __restrict__ src, _Float16* __restrict__ dst, int n4) {
  int i = blockIdx.x * blockDim.x + threadIdx.x;
  if (i >= n4) return;
  float4 v = ((const float4*)src)[i];
  ((uint2*)dst)[i] = make_uint2(pk2h(v.x, v.y), pk2h(v.z, v.w));
}

// ---------------- bf16 transpose: [n][128] -> [128][n] ----------------
__global__ void tr_bf16(const ushort* __restrict__ src, ushort* __restrict__ dT, int n) {
  int i = blockIdx.x * blockDim.x + threadIdx.x;
  if (i >= n * DIM) return;
  int r = i >> 7, d = i & 127;
  dT[(size_t)d * n + r] = src[i];
}

// ---------------- fp32 NT GEMM with fused output conversion ----------------
// OM: 0 = fp32 C; 1 = bf16 Cb only; 2 = fp32 C + f16 Ch copy
template<bool RELU, int OM>
__global__ __launch_bounds__(256) void gemm_nt(
    const float* __restrict__ A, const float* __restrict__ B,
    float* __restrict__ C, ushort* __restrict__ Cb, _Float16* __restrict__ Ch,
    int ldc, int K, const float* __restrict__ bias)
{
  __shared__ float As[64][17];
  __shared__ float Bs[64][17];
  int tid = threadIdx.x;
  int tx = tid & 15, ty = tid >> 4;
  int rowBase = blockIdx.y * 64, colBase = blockIdx.x * 64;
  int lr = tid >> 2, lk = (tid & 3) * 4;
  float acc[4][4] = {};
  for (int k0 = 0; k0 < K; k0 += 16) {
    float4 av = *(const float4*)&A[(size_t)(rowBase + lr) * K + k0 + lk];
    float4 bv = *(const float4*)&B[(size_t)(colBase + lr) * K + k0 + lk];
    As[lr][lk+0]=av.x; As[lr][lk+1]=av.y; As[lr][lk+2]=av.z; As[lr][lk+3]=av.w;
    Bs[lr][lk+0]=bv.x; Bs[lr][lk+1]=bv.y; Bs[lr][lk+2]=bv.z; Bs[lr][lk+3]=bv.w;
    __syncthreads();
#pragma unroll
    for (int kk = 0; kk < 16; ++kk) {
      float a0=As[ty*4+0][kk], a1=As[ty*4+1][kk], a2=As[ty*4+2][kk], a3=As[ty*4+3][kk];
      float b0=Bs[tx*4+0][kk], b1=Bs[tx*4+1][kk], b2=Bs[tx*4+2][kk], b3=Bs[tx*4+3][kk];
      acc[0][0]+=a0*b0; acc[0][1]+=a0*b1; acc[0][2]+=a0*b2; acc[0][3]+=a0*b3;
      acc[1][0]+=a1*b0; acc[1][1]+=a1*b1; acc[1][2]+=a1*b2; acc[1][3]+=a1*b3;
      acc[2][0]+=a2*b0; acc[2][1]+=a2*b1; acc[2][2]+=a2*b2; acc[2][3]+=a2*b3;
      acc[3][0]+=a3*b0; acc[3][1]+=a3*b1; acc[3][2]+=a3*b2; acc[3][3]+=a3*b3;
    }
    __syncthreads();
  }
  int row = rowBase + ty*4, col = colBase + tx*4;
#pragma unroll
  for (int i = 0; i < 4; ++i) {
    float v[4];
#pragma unroll
    for (int j = 0; j < 4; ++j) {
      float x = acc[i][j] + bias[col + j];
      if (RELU) x = fmaxf(x, 0.f);
      v[j] = x;
    }
    size_t base = (size_t)(row + i) * ldc + col;
    if (OM == 1) {
      *(uint2*)&Cb[base] = make_uint2(pk2bf(v[0], v[1]), pk2bf(v[2], v[3]));
    } else {
      float* cp = &C[base];
      *(float2*)cp = make_float2(v[0], v[1]);
      *(float2*)(cp+2) = make_float2(v[2], v[3]);
      if (OM == 2)
        *(uint2*)&Ch[base] = make_uint2(pk2h(v[0], v[1]), pk2h(v[2], v[3]));
    }
  }
}

// ---------------- MFMA bf16: C[n][m] = bf16( dot(A[n],B[m]) * adj[n][m] ) ----------------
#define LDT 136
__global__ __launch_bounds__(256) void mfma_nt_adj(
    const ushort* __restrict__ A, const ushort* __restrict__ B,
    ushort* __restrict__ C, int ldc,
    const float* __restrict__ adj, int ldadj)
{
  __shared__ ushort As[128][LDT];
  __shared__ ushort Bs[128][LDT];
  int tid = threadIdx.x;
  int rowBase = blockIdx.y * 128, colBase = blockIdx.x * 128;
#pragma unroll
  for (int it = 0; it < 8; ++it) {
    int c = it * 256 + tid;
    int r = c >> 4, ch = (c & 15) * 8;
    *(uint4*)&As[r][ch] = *(const uint4*)&A[(size_t)(rowBase + r) * DIM + ch];
    *(uint4*)&Bs[r][ch] = *(const uint4*)&B[(size_t)(colBase + r) * DIM + ch];
  }
  __syncthreads();
  int lane = tid & 63;
  int wv = tid >> 6, wr = wv >> 1, wc = wv & 1;
  int lr = lane & 15, lk = (lane >> 4) * 8;
  f4v acc[4][4] = {};
#pragma unroll
  for (int kc = 0; kc < 4; ++kc) {
    s8v a[4], b[4];
#pragma unroll
    for (int i = 0; i < 4; ++i) {
      a[i] = *(const s8v*)&As[wr*64 + i*16 + lr][kc*32 + lk];
      b[i] = *(const s8v*)&Bs[wc*64 + i*16 + lr][kc*32 + lk];
    }
#pragma unroll
    for (int i = 0; i < 4; ++i)
#pragma unroll
      for (int j = 0; j < 4; ++j)
        acc[i][j] = __builtin_amdgcn_mfma_f32_16x16x32_bf16(a[i], b[j], acc[i][j], 0, 0, 0);
  }
  int rsub = (lane >> 4) * 4;
#pragma unroll
  for (int i = 0; i < 4; ++i)
#pragma unroll
    for (int j = 0; j < 4; ++j) {
      int col = colBase + wc*64 + j*16 + lr;
#pragma unroll
      for (int rg = 0; rg < 4; ++rg) {
        int row = rowBase + wr*64 + i*16 + rsub + rg;
        float v = acc[i][j][rg] * adj[(size_t)row * ldadj + col];
        C[(size_t)row * ldc + col] = f2bf(v);
      }
    }
}

// ---------------- MFMA f16: C[n][m] = dot(A[n],B[m])  (fp32 out) ----------------
__global__ __launch_bounds__(256) void mfma_nt_f32(
    const _Float16* __restrict__ A, const _Float16* __restrict__ B,
    float* __restrict__ C, int ldc)
{
  __shared__ ushort As[128][LDT];
  __shared__ ushort Bs[128][LDT];
  int tid = threadIdx.x;
  int rowBase = blockIdx.y * 128, colBase = blockIdx.x * 128;
#pragma unroll
  for (int it = 0; it < 8; ++it) {
    int c = it * 256 + tid;
    int r = c >> 4, ch = (c & 15) * 8;
    *(uint4*)&As[r][ch] = *(const uint4*)&A[(size_t)(rowBase + r) * DIM + ch];
    *(uint4*)&Bs[r][ch] = *(const uint4*)&B[(size_t)(colBase + r) * DIM + ch];
  }
  __syncthreads();
  int lane = tid & 63;
  int wv = tid >> 6, wr = wv >> 1, wc = wv & 1;
  int lr = lane & 15, lk = (lane >> 4) * 8;
  f4v acc[4][4] = {};
#pragma unroll
  for (int kc = 0; kc < 4; ++kc) {
    h8v a[4], b[4];
#pragma unroll
    for (int i = 0; i < 4; ++i) {
      a[i] = *(const h8v*)&As[wr*64 + i*16 + lr][kc*32 + lk];
      b[i] = *(const h8v*)&Bs[wc*64 + i*16 + lr][kc*32 + lk];
    }
#pragma unroll
    for (int i = 0; i < 4; ++i)
#pragma unroll
      for (int j = 0; j < 4; ++j)
        acc[i][j] = __builtin_amdgcn_mfma_f32_16x16x32_f16(a[i], b[j], acc[i][j], 0, 0, 0);
  }
  int rsub = (lane >> 4) * 4;
#pragma unroll
  for (int i = 0; i < 4; ++i)
#pragma unroll
    for (int j = 0; j < 4; ++j) {
      int col = colBase + wc*64 + j*16 + lr;
#pragma unroll
      for (int rg = 0; rg < 4; ++rg) {
        int row = rowBase + wr*64 + i*16 + rsub + rg;
        C[(size_t)row * ldc + col] = acc[i][j][rg];
      }
    }
}

// ---------------- MFMA f16: Wx[m][j] = dot(wvb[m], Wih[brow(j)]) + bias[brow(j)] ----------------
__global__ __launch_bounds__(256) void mfma_wx(
    const _Float16* __restrict__ A, const _Float16* __restrict__ Bw,
    const float* __restrict__ bias, float* __restrict__ out)
{
  __shared__ ushort As[128][LDT];
  __shared__ ushort Bs[128][LDT];
  int tid = threadIdx.x;
  int m0 = blockIdx.y * 128, colBase = blockIdx.x * 128;
#pragma unroll
  for (int it = 0; it < 8; ++it) {
    int c = it * 256 + tid;
    int r = c >> 4, ch = (c & 15) * 8;
    *(uint4*)&As[r][ch] = *(const uint4*)&A[(size_t)(m0 + r) * DIM + ch];
    int j = colBase + r;
    int brow = 128 * (j & 3) + (j >> 2);
    *(uint4*)&Bs[r][ch] = *(const uint4*)&Bw[(size_t)brow * DIM + ch];
  }
  __syncthreads();
  int lane = tid & 63;
  int wv = tid >> 6, wr = wv >> 1, wc = wv & 1;
  int lr = lane & 15, lk = (lane >> 4) * 8;
  f4v acc[4][4] = {};
#pragma unroll
  for (int kc = 0; kc < 4; ++kc) {
    h8v a[4], b[4];
#pragma unroll
    for (int i = 0; i < 4; ++i) {
      a[i] = *(const h8v*)&As[wr*64 + i*16 + lr][kc*32 + lk];
      b[i] = *(const h8v*)&Bs[wc*64 + i*16 + lr][kc*32 + lk];
    }
#pragma unroll
    for (int i = 0; i < 4; ++i)
#pragma unroll
      for (int j = 0; j < 4; ++j)
        acc[i][j] = __builtin_amdgcn_mfma_f32_16x16x32_f16(a[i], b[j], acc[i][j], 0, 0, 0);
  }
  int rsub = (lane >> 4) * 4;
#pragma unroll
  for (int i = 0; i < 4; ++i)
#pragma unroll
    for (int j = 0; j < 4; ++j) {
      int col = colBase + wc*64 + j*16 + lr;
      int brow = 128 * (col & 3) + (col >> 2);
      float bv = bias[brow];
#pragma unroll
      for (int rg = 0; rg < 4; ++rg) {
        int row = m0 + wr*64 + i*16 + rsub + rg;
        out[(size_t)row * 512 + col] = acc[i][j][rg] + bv;
      }
    }
}

// ---------------- MFMA bf16: pt[kc][n][d] = sum_{m in chunk} attn[n][m] * hs[m][d] ----------------
#define LDT2 72
__global__ __launch_bounds__(256) void mfma_av(
    const ushort* __restrict__ attnb, const ushort* __restrict__ hsT,
    float* __restrict__ pt, int chunk, int N)
{
  __shared__ ushort As[128][LDT2];
  __shared__ ushort Bs[128][LDT2];
  int tid = threadIdx.x;
  int n0 = blockIdx.x * 128;
  int m0 = blockIdx.y * chunk;
  int lane = tid & 63;
  int wv = tid >> 6, wr = wv >> 1, wc = wv & 1;
  int lr = lane & 15, lk = (lane >> 4) * 8;
  f4v acc[4][4] = {};
  for (int mt = 0; mt < chunk; mt += 64) {
#pragma unroll
    for (int it = 0; it < 4; ++it) {
      int c = it * 256 + tid;
      int r = c >> 3, ch = (c & 7) * 8;
      *(uint4*)&As[r][ch] = *(const uint4*)&attnb[(size_t)(n0 + r) * N + m0 + mt + ch];
      *(uint4*)&Bs[r][ch] = *(const uint4*)&hsT[(size_t)r * N + m0 + mt + ch];
    }
    __syncthreads();
#pragma unroll
    for (int kc = 0; kc < 2; ++kc) {
      s8v a[4], b[4];
#pragma unroll
      for (int i = 0; i < 4; ++i) {
        a[i] = *(const s8v*)&As[wr*64 + i*16 + lr][kc*32 + lk];
        b[i] = *(const s8v*)&Bs[wc*64 + i*16 + lr][kc*32 + lk];
      }
#pragma unroll
      for (int i = 0; i < 4; ++i)
#pragma unroll
        for (int j = 0; j < 4; ++j)
          acc[i][j] = __builtin_amdgcn_mfma_f32_16x16x32_bf16(a[i], b[j], acc[i][j], 0, 0, 0);
    }
    __syncthreads();
  }
  size_t base = ((size_t)blockIdx.y * N + n0) * DIM;
  int rsub = (lane >> 4) * 4;
#pragma unroll
  for (int i = 0; i < 4; ++i)
#pragma unroll
    for (int j = 0; j < 4; ++j) {
      int d = wc*64 + j*16 + lr;
#pragma unroll
      for (int rg = 0; rg < 4; ++rg) {
        int nn = wr*64 + i*16 + rsub + rg;
        pt[base + (size_t)nn * DIM + d] = acc[i][j][rg];
      }
    }
}

// ---------------- row abs-sum over bf16 matrix ----------------
__global__ void row_reduce_abs_bf16(const ushort* __restrict__ W, int ld, int M,
                                    float* __restrict__ out, float eps) {
  int n = blockIdx.x;
  const ushort* row = W + (size_t)n * ld;
  float s = 0;
  for (int m = threadIdx.x * 8; m < M; m += 256 * 8) {
    uint4 v = *(const uint4*)&row[m];
    unsigned a[4] = {v.x, v.y, v.z, v.w};
#pragma unroll
    for (int q = 0; q < 4; ++q) {
      s += __int_as_float((int)((a[q] & 0x7FFFu) << 16));
      s += __int_as_float((int)(a[q] & 0x7FFF0000u));
    }
  }
  __shared__ float red[256];
  red[threadIdx.x] = s; __syncthreads();
  for (int k = 128; k > 0; k >>= 1) {
    if (threadIdx.x < k) red[threadIdx.x] += red[threadIdx.x + k];
    __syncthreads();
  }
  if (threadIdx.x == 0) out[n] = fmaxf(red[0], eps);
}

// ---------------- row mean (fp32) ----------------
__global__ void row_mean(const float* __restrict__ W, int ld, int M,
                         float* __restrict__ out, float inv) {
  int n = blockIdx.x;
  const float* row = W + (size_t)n * ld;
  float s = 0;
  for (int m = threadIdx.x; m < M; m += 256) s += row[m];
  __shared__ float red[256];
  red[threadIdx.x] = s; __syncthreads();
  for (int k = 128; k > 0; k >>= 1) {
    if (threadIdx.x < k) red[threadIdx.x] += red[threadIdx.x + k];
    __syncthreads();
  }
  if (threadIdx.x == 0) out[n] = red[0] * inv;
}

// ---------------- column mean, 2-stage ----------------
__global__ void colmean_part(const float* __restrict__ W, int ld, int rows_per,
                             float* __restrict__ part, int M) {
  int m = blockIdx.x * blockDim.x + threadIdx.x;
  int n0 = blockIdx.y * rows_per;
  float s = 0;
  for (int n = 0; n < rows_per; ++n) s += W[(size_t)(n0 + n) * ld + m];
  part[(size_t)blockIdx.y * M + m] = s;
}
__global__ void colmean_fin(const float* __restrict__ part, int M, int nparts,
                            float* __restrict__ out, float inv) {
  int m = blockIdx.x * blockDim.x + threadIdx.x;
  float s = 0;
  for (int k = 0; k < nparts; ++k) s += part[(size_t)k * M + m];
  out[m] = s * inv;
}

// xs[n][d] += (sum_kc pt[kc][n][d]) / denom[n]
__global__ void axpy_reduce(const float* __restrict__ pt, const float* __restrict__ denom,
                            float* __restrict__ xs, int total) {
  int i = blockIdx.x * blockDim.x + threadIdx.x;
  if (i >= total) return;
  float s = 0;
#pragma unroll
  for (int k = 0; k < 8; ++k) s += pt[(size_t)k * total + i];
  xs[i] += s / denom[i >> 7];
}

__global__ void add_vec(const float* __restrict__ a, const float* __restrict__ b,
                        float* __restrict__ o, int n) {
  int i = blockIdx.x * blockDim.x + threadIdx.x;
  if (i < n) o[i] = a[i] + b[i];
}

// ---------------- bidirectional LSTM v10p: v10 + PRE-CONVERTED f16 weights ----------------
// Round-20 analysis: v10's 900 busy-cyc/SIMD/step includes the remat'd LOADW
// = 64 v_cvt_pkrtz + 256B fp32 L1 reads per thread PER STEP. Weights now
// pre-converted to f16 in global memory: remat unit = 8 pure uint4 loads
// (64B/thread, zero cvt). Identical f16 values -> identical numerics.
#define REP8(X) X(0) X(1) X(2) X(3) X(4) X(5) X(6) X(7)

__global__ __launch_bounds__(512, 2) void lstm_kernel(
    const _Float16* __restrict__ WhhH,  // [2][512][128] f16 (pre-converted)
    const float* __restrict__ Wxp,      // [2][M][512]  gate-interleaved: col 4u+g
    float* __restrict__ xs_rnn,         // [M][256]
    int M)
{
  int dir = blockIdx.x;
  int tid = threadIdx.x;
  int w = tid >> 6, lane = tid & 63;
  int u  = w * 16 + (lane >> 2);
  int gp = (lane >> 1) & 1;          // 0={i,f} 1={g,o}
  int kh = lane & 1;
  int row0 = gp ? (256 + u) : u;
  const _Float16* base = WhhH + (size_t)dir * 512 * DIM;
  const uint4* w0p = (const uint4*)(base + (size_t)row0 * DIM + kh * 64);
  const uint4* w1p = (const uint4*)(base + (size_t)(row0 + 128) * DIM + kh * 64);

#define DECLW(r) uint4 wA##r, wB##r;
  REP8(DECLW)
#define LOADW(r) { wA##r = w0p[r]; wB##r = w1p[r]; }
  REP8(LOADW)

  __shared__ __align__(16) _Float16 hbuf[2][DIM];
  if (tid < DIM) hbuf[0][tid] = (_Float16)0.f;
  float c = 0.f;
  __syncthreads();

  const float* WxD = Wxp + (size_t)dir * M * 512;
  int wxcol = 4 * u + 2 * gp;
  int t0 = dir ? (M - 1) : 0;
  float2 wx = *(const float2*)&WxD[(size_t)t0 * 512 + wxcol];
  for (int s = 0; s < M; ++s) {
    int t = dir ? (M - 1 - s) : s;
    float2 wxn = make_float2(0.f, 0.f);
    if (s + 1 < M) {
      int tn = dir ? (M - 2 - s) : (s + 1);
      wxn = *(const float2*)&WxD[(size_t)tn * 512 + wxcol];
    }
    int cur = s & 1;
    const uint4* hb = (const uint4*)(hbuf[cur]) + kh * 8;
    float a0 = 0.f, a1 = 0.f;
#define DOTW(r) { uint4 hv = hb[r]; a0 = dot8u(wA##r, hv, a0); a1 = dot8u(wB##r, hv, a1); }
    REP8(DOTW)
    float z0 = dpp_xadd<0xB1>(a0) + wx.x;
    float z1 = dpp_xadd<0xB1>(a1) + wx.y;
    float av0 = gp ? tanh_fast(z0) : sigm_fast(z0);
    float av1 = sigm_fast(z1);
    float gv = dpp_movf<0x102>(av0);
    float ov = dpp_movf<0x102>(av1);
    if ((lane & 3) == 0) {
      c = av1 * c + av0 * gv;
      float hv = ov * tanh_fast(c);
      hbuf[cur ^ 1][u] = (_Float16)hv;
      xs_rnn[(size_t)t * (2 * DIM) + dir * DIM + u] = fmaxf(hv, 0.f);
    }
    wx = wxn;
    __syncthreads();
  }
#undef DOTW
#undef LOADW
#undef DECLW
#undef REP8
}

// ---------------- weighted mean pooling, 2-stage (multi-block) ----------------
__global__ void pool_part(const float* __restrict__ mat, const float* __restrict__ wv,
                          int chunk, float* __restrict__ part) {
  int t = threadIdx.x; int g = t >> 7, d = t & 127;
  int r0 = blockIdx.x * chunk;
  float acc = 0;
  for (int r = g; r < chunk; r += 8) acc += wv[r0 + r] * mat[(size_t)(r0 + r) * DIM + d];
  __shared__ float red[1024];
  red[t] = acc; __syncthreads();
  if (g == 0) {
    float s = acc;
#pragma unroll
    for (int k = 1; k < 8; ++k) s += red[k * 128 + d];
    part[(size_t)blockIdx.x * DIM + d] = s;
  }
}
__global__ void pool_fin(const float* __restrict__ part, int nparts,
                         float* __restrict__ out, float inv) {
  int d = threadIdx.x;
  float s = 0;
  for (int k = 0; k < nparts; ++k) s += part[(size_t)k * DIM + d];
  out[d] = s * inv;
}

// ---------------- output MLP (1024 thr, 4-way k-split per neuron) ----------------
__global__ void mlp_kernel(const float* __restrict__ cvec, const float* __restrict__ pvec,
                           const float* __restrict__ Wo, const float* __restrict__ bo,
                           const float* __restrict__ Wi, const float* __restrict__ bi,
                           float* __restrict__ out) {
  __shared__ float buf0[256], buf1[256];
  __shared__ float red[1024];
  int t = threadIdx.x;
  int nr = t >> 2, part = t & 3;       // neuron, k-part (64 elems each)
  if (t < 128) buf0[t] = cvec[t];
  else if (t < 256) buf0[t] = pvec[t - 128];
  __syncthreads();
  {
    const float* W = Wo + (size_t)nr * 256 + part * 64;
    const float* x = buf0 + part * 64;
    float s = 0;
    for (int v = 0; v < 64; ++v) s += W[v] * x[v];
    red[t] = s; __syncthreads();
    if (part == 0) buf1[nr] = fmaxf(red[t] + red[t+1] + red[t+2] + red[t+3] + bo[nr], 0.f);
  }
  __syncthreads();
  {
    const float* W = Wo + 256 * 256 + (size_t)nr * 256 + part * 64;
    const float* x = buf1 + part * 64;
    float s = 0;
    for (int v = 0; v < 64; ++v) s += W[v] * x[v];
    red[t] = s; __syncthreads();
    if (part == 0) buf0[nr] = fmaxf(red[t] + red[t+1] + red[t+2] + red[t+3] + bo[256 + nr], 0.f);
  }
  __syncthreads();
  if (t < 8) {
    int o = t >> 2, p = t & 3;
    const float* W = Wi + (size_t)o * 256 + p * 64;
    const float* x = buf0 + p * 64;
    float s = 0;
    for (int v = 0; v < 64; ++v) s += W[v] * x[v];
    red[t] = s;
  }
  __syncthreads();
  if (t < 2)
    out[t] = red[4*t] + red[4*t+1] + red[4*t+2] + red[4*t+3] + bi[t];
}

extern "C" void kernel_launch(void* const* d_in, const int* in_sizes, int n_in,
                              void* d_out, int out_size, void* d_ws, size_t ws_size,
                              hipStream_t stream) {
  const int*   fingerprints = (const int*)d_in[0];
  const float* adjacency    = (const float*)d_in[1];
  const int*   words        = (const int*)d_in[2];
  const float* emb_fp       = (const float*)d_in[3];
  const float* emb_word     = (const float*)d_in[4];
  const float* Wg  = (const float*)d_in[5];
  const float* bg  = (const float*)d_in[6];
  const float* Wih = (const float*)d_in[7];
  const float* Whh = (const float*)d_in[8];
  const float* bih = (const float*)d_in[9];
  const float* bhh = (const float*)d_in[10];
  const float* Wc  = (const float*)d_in[11];
  const float* bc  = (const float*)d_in[12];
  const float* Wp  = (const float*)d_in[13];
  const float* bp  = (const float*)d_in[14];
  const float* Wo  = (const float*)d_in[15];
  const float* bo  = (const float*)d_in[16];
  const float* Wi  = (const float*)d_in[17];
  const float* bi  = (const float*)d_in[18];

  const int N = in_sizes[0];
  const int M = in_sizes[2];
  const int LGAT = in_sizes[5] / (DIM * DIM);

  float* out  = (float*)d_out;
  float* attn = out + 2;                 // [N][M] fp32: final `weights`
  ushort* attnb = (ushort*)attn;         // bf16 scratch during GAT

  float* ws = (float*)d_ws;
  size_t off = 0;
  auto alloc = [&](size_t nf) { float* p = ws + off; off += (nf + 3) & ~(size_t)3; return p; };
  float* xs     = alloc((size_t)N * DIM);
  float* wvb    = alloc((size_t)M * DIM);
  float* denom  = alloc(N);
  float* pt     = alloc((size_t)8 * N * DIM);    // K-split partials; aliased as Wx
  float* Wx     = pt;                            // [2][M][512] gate-interleaved
  float* xs_rnn = alloc((size_t)M * 2 * DIM);
  float* hp     = alloc((size_t)M * DIM);
  float* hmat   = alloc((size_t)N * DIM);
  float* bsum   = alloc(1024);
  float* wcomp  = alloc(N);
  float* wprot  = alloc(M);
  float* cvec   = alloc(DIM);
  float* pvec   = alloc(DIM);
  float* cpart  = alloc((size_t)32 * M);
  float* ppart  = alloc((size_t)16 * DIM);
  ushort* hs_b  = (ushort*)alloc((size_t)N * DIM / 2);   // hs bf16
  ushort* hsT_b = (ushort*)alloc((size_t)N * DIM / 2);   // hs^T bf16 [128][N]
  _Float16* wvb_h  = (_Float16*)alloc((size_t)M * DIM / 2);
  _Float16* wih_h  = (_Float16*)alloc((size_t)2 * 512 * DIM / 2);
  _Float16* whh_h  = (_Float16*)alloc((size_t)2 * 512 * DIM / 2);
  _Float16* hmat_h = (_Float16*)alloc((size_t)N * DIM / 2);
  _Float16* hp_h   = (_Float16*)alloc((size_t)M * DIM / 2);
  (void)ws_size; (void)n_in; (void)out_size;

  // ---- embeddings ----
  gather_rows<<<(N * 32 + 255) / 256, 256, 0, stream>>>(emb_fp, fingerprints, xs, N);
  gather_rows_wv<<<(M * 32 + 255) / 256, 256, 0, stream>>>(emb_word, words, wvb, wvb_h, M);

  // ---- GAT layers (bf16 MFMA inner loop; hs produced directly in bf16) ----
  for (int l = 0; l < LGAT; ++l) {
    gemm_nt<true, 1><<<dim3(DIM / 64, N / 64), 256, 0, stream>>>(
        xs, Wg + (size_t)l * DIM * DIM, nullptr, hs_b, nullptr, DIM, DIM, bg + l * DIM);
    tr_bf16<<<(N * DIM) / 256, 256, 0, stream>>>(hs_b, hsT_b, N);
    mfma_nt_adj<<<dim3(N / 128, N / 128), 256, 0, stream>>>(
        hs_b, hs_b, attnb, N, adjacency, N);
    row_reduce_abs_bf16<<<N, 256, 0, stream>>>(attnb, N, N, denom, 1e-12f);
    mfma_av<<<dim3(N / 128, 8), 256, 0, stream>>>(attnb, hsT_b, pt, N / 8, N);
    axpy_reduce<<<(N * DIM) / 256, 256, 0, stream>>>(pt, denom, xs, N * DIM);
  }

  // ---- LSTM precompute (f16 MFMA Wx; pre-convert Whh to f16) + run ----
  add_vec<<<4, 256, 0, stream>>>(bih, bhh, bsum, 1024);
  conv_f16<<<(2 * 512 * DIM / 4 + 255) / 256, 256, 0, stream>>>(Wih, wih_h, 2 * 512 * DIM / 4);
  conv_f16<<<(2 * 512 * DIM / 4 + 255) / 256, 256, 0, stream>>>(Whh, whh_h, 2 * 512 * DIM / 4);
  for (int d = 0; d < 2; ++d) {
    mfma_wx<<<dim3(512 / 128, M / 128), 256, 0, stream>>>(
        wvb_h, wih_h + (size_t)d * 512 * DIM, bsum + d * 512, Wx + (size_t)d * M * 512);
  }
  lstm_kernel<<<2, 512, 0, stream>>>(whh_h, Wx, xs_rnn, M);

  // ---- cross-attention pooling (f16 copies fused into GEMM epilogues) ----
  gemm_nt<true, 2><<<dim3(DIM / 64, M / 64), 256, 0, stream>>>(
      xs_rnn, Wp, hp, nullptr, hp_h, DIM, 2 * DIM, bp);
  gemm_nt<true, 2><<<dim3(DIM / 64, N / 64), 256, 0, stream>>>(
      xs, Wc, hmat, nullptr, hmat_h, DIM, DIM, bc);
  mfma_nt_f32<<<dim3(M / 128, N / 128), 256, 0, stream>>>(hmat_h, hp_h, attn, M);
  row_mean<<<N, 256, 0, stream>>>(attn, M, M, wcomp, 1.f / (float)M);
  colmean_part<<<dim3(M / 256, 32), 256, 0, stream>>>(attn, M, N / 32, cpart, M);
  colmean_fin<<<M / 256, 256, 0, stream>>>(cpart, M, 32, wprot, 1.f / (float)N);
  pool_part<<<16, 1024, 0, stream>>>(hmat, wcomp, N / 16, ppart);
  pool_fin<<<1, DIM, 0, stream>>>(ppart, 16, cvec, 1.f / (float)N);
  pool_part<<<16, 1024, 0, stream>>>(hp, wprot, M / 16, ppart);
  pool_fin<<<1, DIM, 0, stream>>>(ppart, 16, pvec, 1.f / (float)M);

  // ---- output MLP ----
  mlp_kernel<<<1, 1024, 0, stream>>>(cvec, pvec, Wo, bo, Wi, bi, out);
}

// Round 22
// 2673.718 us; speedup vs baseline: 1.0315x; 1.0315x over previous
//
#include <hip/hip_runtime.h>
#include <hip/hip_bf16.h>
#include <math.h>

#define DIM 128

typedef float v2f __attribute__((ext_vector_type(2)));
typedef _Float16 v2h __attribute__((ext_vector_type(2)));
typedef _Float16 h8v __attribute__((ext_vector_type(8)));  // 8 f16 (4 VGPR) MFMA frag
typedef short s8v __attribute__((ext_vector_type(8)));     // 8 bf16 (4 VGPR)
typedef float f4v __attribute__((ext_vector_type(4)));

// DPP move: lane i <- lane i+N (row_shl:N) or quad_perm etc. VALU-speed.
template<int CTRL>
__device__ inline float dpp_movf(float v) {
  int x = __builtin_amdgcn_update_dpp(0, __float_as_int(v), CTRL, 0xF, 0xF, true);
  return __int_as_float(x);
}
template<int CTRL>
__device__ inline float dpp_xadd(float v) { return v + dpp_movf<CTRL>(v); }

// 8-wide f16 dot, fp32 accum, operands pre-packed in uint4 (bit_cast = free)
__device__ inline float dot8u(uint4 a, uint4 b, float acc) {
#if __has_builtin(__builtin_amdgcn_fdot2)
  acc = __builtin_amdgcn_fdot2(__builtin_bit_cast(v2h, a.x), __builtin_bit_cast(v2h, b.x), acc, false);
  acc = __builtin_amdgcn_fdot2(__builtin_bit_cast(v2h, a.y), __builtin_bit_cast(v2h, b.y), acc, false);
  acc = __builtin_amdgcn_fdot2(__builtin_bit_cast(v2h, a.z), __builtin_bit_cast(v2h, b.z), acc, false);
  acc = __builtin_amdgcn_fdot2(__builtin_bit_cast(v2h, a.w), __builtin_bit_cast(v2h, b.w), acc, false);
#else
  const v2h* pa = (const v2h*)&a; const v2h* pb = (const v2h*)&b;
#pragma unroll
  for (int i = 0; i < 4; ++i) {
    acc += (float)pa[i][0] * (float)pb[i][0];
    acc += (float)pa[i][1] * (float)pb[i][1];
  }
#endif
  return acc;
}

__device__ inline unsigned pk2h(float a, float b) {
  return __builtin_bit_cast(unsigned, __builtin_amdgcn_cvt_pkrtz(a, b));
}
__device__ inline float sigm_fast(float z) {
  return __builtin_amdgcn_rcpf(1.f + __expf(-z));
}
__device__ inline float tanh_fast(float z) {
  float e = __expf(-2.f * z);
  return (1.f - e) * __builtin_amdgcn_rcpf(1.f + e);
}
// fp32 -> bf16 RNE
__device__ inline ushort f2bf(float x) {
  unsigned u = __builtin_bit_cast(unsigned, x);
  return (ushort)((u + 0x7FFFu + ((u >> 16) & 1u)) >> 16);
}
__device__ inline unsigned pk2bf(float a, float b) {
  return (unsigned)f2bf(a) | ((unsigned)f2bf(b) << 16);
}

// ---------------- gather rows from embedding table ----------------
__global__ void gather_rows(const float* __restrict__ table, const int* __restrict__ idx,
                            float* __restrict__ dst, int n) {
  int i = blockIdx.x * blockDim.x + threadIdx.x;
  int total = n * 32;
  if (i >= total) return;
  int r = i >> 5, c = i & 31;
  const float4* src = (const float4*)table + (size_t)idx[r] * 32 + c;
  ((float4*)dst)[i] = *src;
}
// gather + f16 copy (for wvb)
__global__ void gather_rows_wv(const float* __restrict__ table, const int* __restrict__ idx,
                               float* __restrict__ dst, _Float16* __restrict__ dsth, int n) {
  int i = blockIdx.x * blockDim.x + threadIdx.x;
  int total = n * 32;
  if (i >= total) return;
  int r = i >> 5, c = i & 31;
  float4 v = ((const float4*)table)[(size_t)idx[r] * 32 + c];
  ((float4*)dst)[i] = v;
  ((uint2*)dsth)[i] = make_uint2(pk2h(v.x, v.y), pk2h(v.z, v.w));
}

// ---------------- fp32 -> f16 convert ----------------
__global__ void conv_f16(const float* __restrict__ src, _Float16* __restrict__ dst, int n4) {
  int i = blockIdx.x * blockDim.x + threadIdx.x;
  if (i >= n4) return;
  float4 v = ((const float4*)src)[i];
  ((uint2*)dst)[i] = make_uint2(pk2h(v.x, v.y), pk2h(v.z, v.w));
}

// ---------------- bf16 transpose: [n][128] -> [128][n] ----------------
__global__ void tr_bf16(const ushort* __restrict__ src, ushort* __restrict__ dT, int n) {
  int i = blockIdx.x * blockDim.x + threadIdx.x;
  if (i >= n * DIM) return;
  int r = i >> 7, d = i & 127;
  dT[(size_t)d * n + r] = src[i];
}

// ---------------- fp32 NT GEMM with fused output conversion ----------------
// OM: 0 = fp32 C; 1 = bf16 Cb only; 2 = fp32 C + f16 Ch copy
template<bool RELU, int OM>
__global__ __launch_bounds__(256) void gemm_nt(
    const float* __restrict__ A, const float* __restrict__ B,
    float* __restrict__ C, ushort* __restrict__ Cb, _Float16* __restrict__ Ch,
    int ldc, int K, const float* __restrict__ bias)
{
  __shared__ float As[64][17];
  __shared__ float Bs[64][17];
  int tid = threadIdx.x;
  int tx = tid & 15, ty = tid >> 4;
  int rowBase = blockIdx.y * 64, colBase = blockIdx.x * 64;
  int lr = tid >> 2, lk = (tid & 3) * 4;
  float acc[4][4] = {};
  for (int k0 = 0; k0 < K; k0 += 16) {
    float4 av = *(const float4*)&A[(size_t)(rowBase + lr) * K + k0 + lk];
    float4 bv = *(const float4*)&B[(size_t)(colBase + lr) * K + k0 + lk];
    As[lr][lk+0]=av.x; As[lr][lk+1]=av.y; As[lr][lk+2]=av.z; As[lr][lk+3]=av.w;
    Bs[lr][lk+0]=bv.x; Bs[lr][lk+1]=bv.y; Bs[lr][lk+2]=bv.z; Bs[lr][lk+3]=bv.w;
    __syncthreads();
#pragma unroll
    for (int kk = 0; kk < 16; ++kk) {
      float a0=As[ty*4+0][kk], a1=As[ty*4+1][kk], a2=As[ty*4+2][kk], a3=As[ty*4+3][kk];
      float b0=Bs[tx*4+0][kk], b1=Bs[tx*4+1][kk], b2=Bs[tx*4+2][kk], b3=Bs[tx*4+3][kk];
      acc[0][0]+=a0*b0; acc[0][1]+=a0*b1; acc[0][2]+=a0*b2; acc[0][3]+=a0*b3;
      acc[1][0]+=a1*b0; acc[1][1]+=a1*b1; acc[1][2]+=a1*b2; acc[1][3]+=a1*b3;
      acc[2][0]+=a2*b0; acc[2][1]+=a2*b1; acc[2][2]+=a2*b2; acc[2][3]+=a2*b3;
      acc[3][0]+=a3*b0; acc[3][1]+=a3*b1; acc[3][2]+=a3*b2; acc[3][3]+=a3*b3;
    }
    __syncthreads();
  }
  int row = rowBase + ty*4, col = colBase + tx*4;
#pragma unroll
  for (int i = 0; i < 4; ++i) {
    float v[4];
#pragma unroll
    for (int j = 0; j < 4; ++j) {
      float x = acc[i][j] + bias[col + j];
      if (RELU) x = fmaxf(x, 0.f);
      v[j] = x;
    }
    size_t base = (size_t)(row + i) * ldc + col;
    if (OM == 1) {
      *(uint2*)&Cb[base] = make_uint2(pk2bf(v[0], v[1]), pk2bf(v[2], v[3]));
    } else {
      float* cp = &C[base];
      *(float2*)cp = make_float2(v[0], v[1]);
      *(float2*)(cp+2) = make_float2(v[2], v[3]);
      if (OM == 2)
        *(uint2*)&Ch[base] = make_uint2(pk2h(v[0], v[1]), pk2h(v[2], v[3]));
    }
  }
}

// ---------------- MFMA bf16: C[n][m] = bf16( dot(A[n],B[m]) * adj[n][m] ) ----------------
#define LDT 136
__global__ __launch_bounds__(256) void mfma_nt_adj(
    const ushort* __restrict__ A, const ushort* __restrict__ B,
    ushort* __restrict__ C, int ldc,
    const float* __restrict__ adj, int ldadj)
{
  __shared__ ushort As[128][LDT];
  __shared__ ushort Bs[128][LDT];
  int tid = threadIdx.x;
  int rowBase = blockIdx.y * 128, colBase = blockIdx.x * 128;
#pragma unroll
  for (int it = 0; it < 8; ++it) {
    int c = it * 256 + tid;
    int r = c >> 4, ch = (c & 15) * 8;
    *(uint4*)&As[r][ch] = *(const uint4*)&A[(size_t)(rowBase + r) * DIM + ch];
    *(uint4*)&Bs[r][ch] = *(const uint4*)&B[(size_t)(colBase + r) * DIM + ch];
  }
  __syncthreads();
  int lane = tid & 63;
  int wv = tid >> 6, wr = wv >> 1, wc = wv & 1;
  int lr = lane & 15, lk = (lane >> 4) * 8;
  f4v acc[4][4] = {};
#pragma unroll
  for (int kc = 0; kc < 4; ++kc) {
    s8v a[4], b[4];
#pragma unroll
    for (int i = 0; i < 4; ++i) {
      a[i] = *(const s8v*)&As[wr*64 + i*16 + lr][kc*32 + lk];
      b[i] = *(const s8v*)&Bs[wc*64 + i*16 + lr][kc*32 + lk];
    }
#pragma unroll
    for (int i = 0; i < 4; ++i)
#pragma unroll
      for (int j = 0; j < 4; ++j)
        acc[i][j] = __builtin_amdgcn_mfma_f32_16x16x32_bf16(a[i], b[j], acc[i][j], 0, 0, 0);
  }
  int rsub = (lane >> 4) * 4;
#pragma unroll
  for (int i = 0; i < 4; ++i)
#pragma unroll
    for (int j = 0; j < 4; ++j) {
      int col = colBase + wc*64 + j*16 + lr;
#pragma unroll
      for (int rg = 0; rg < 4; ++rg) {
        int row = rowBase + wr*64 + i*16 + rsub + rg;
        float v = acc[i][j][rg] * adj[(size_t)row * ldadj + col];
        C[(size_t)row * ldc + col] = f2bf(v);
      }
    }
}

// ---------------- MFMA f16: C[n][m] = dot(A[n],B[m])  (fp32 out) ----------------
__global__ __launch_bounds__(256) void mfma_nt_f32(
    const _Float16* __restrict__ A, const _Float16* __restrict__ B,
    float* __restrict__ C, int ldc)
{
  __shared__ ushort As[128][LDT];
  __shared__ ushort Bs[128][LDT];
  int tid = threadIdx.x;
  int rowBase = blockIdx.y * 128, colBase = blockIdx.x * 128;
#pragma unroll
  for (int it = 0; it < 8; ++it) {
    int c = it * 256 + tid;
    int r = c >> 4, ch = (c & 15) * 8;
    *(uint4*)&As[r][ch] = *(const uint4*)&A[(size_t)(rowBase + r) * DIM + ch];
    *(uint4*)&Bs[r][ch] = *(const uint4*)&B[(size_t)(colBase + r) * DIM + ch];
  }
  __syncthreads();
  int lane = tid & 63;
  int wv = tid >> 6, wr = wv >> 1, wc = wv & 1;
  int lr = lane & 15, lk = (lane >> 4) * 8;
  f4v acc[4][4] = {};
#pragma unroll
  for (int kc = 0; kc < 4; ++kc) {
    h8v a[4], b[4];
#pragma unroll
    for (int i = 0; i < 4; ++i) {
      a[i] = *(const h8v*)&As[wr*64 + i*16 + lr][kc*32 + lk];
      b[i] = *(const h8v*)&Bs[wc*64 + i*16 + lr][kc*32 + lk];
    }
#pragma unroll
    for (int i = 0; i < 4; ++i)
#pragma unroll
      for (int j = 0; j < 4; ++j)
        acc[i][j] = __builtin_amdgcn_mfma_f32_16x16x32_f16(a[i], b[j], acc[i][j], 0, 0, 0);
  }
  int rsub = (lane >> 4) * 4;
#pragma unroll
  for (int i = 0; i < 4; ++i)
#pragma unroll
    for (int j = 0; j < 4; ++j) {
      int col = colBase + wc*64 + j*16 + lr;
#pragma unroll
      for (int rg = 0; rg < 4; ++rg) {
        int row = rowBase + wr*64 + i*16 + rsub + rg;
        C[(size_t)row * ldc + col] = acc[i][j][rg];
      }
    }
}

// ---------------- MFMA f16: Wx[m][j] = dot(wvb[m], Wih[brow(j)]) + bias[brow(j)] ----------------
__global__ __launch_bounds__(256) void mfma_wx(
    const _Float16* __restrict__ A, const _Float16* __restrict__ Bw,
    const float* __restrict__ bias, float* __restrict__ out)
{
  __shared__ ushort As[128][LDT];
  __shared__ ushort Bs[128][LDT];
  int tid = threadIdx.x;
  int m0 = blockIdx.y * 128, colBase = blockIdx.x * 128;
#pragma unroll
  for (int it = 0; it < 8; ++it) {
    int c = it * 256 + tid;
    int r = c >> 4, ch = (c & 15) * 8;
    *(uint4*)&As[r][ch] = *(const uint4*)&A[(size_t)(m0 + r) * DIM + ch];
    int j = colBase + r;
    int brow = 128 * (j & 3) + (j >> 2);
    *(uint4*)&Bs[r][ch] = *(const uint4*)&Bw[(size_t)brow * DIM + ch];
  }
  __syncthreads();
  int lane = tid & 63;
  int wv = tid >> 6, wr = wv >> 1, wc = wv & 1;
  int lr = lane & 15, lk = (lane >> 4) * 8;
  f4v acc[4][4] = {};
#pragma unroll
  for (int kc = 0; kc < 4; ++kc) {
    h8v a[4], b[4];
#pragma unroll
    for (int i = 0; i < 4; ++i) {
      a[i] = *(const h8v*)&As[wr*64 + i*16 + lr][kc*32 + lk];
      b[i] = *(const h8v*)&Bs[wc*64 + i*16 + lr][kc*32 + lk];
    }
#pragma unroll
    for (int i = 0; i < 4; ++i)
#pragma unroll
      for (int j = 0; j < 4; ++j)
        acc[i][j] = __builtin_amdgcn_mfma_f32_16x16x32_f16(a[i], b[j], acc[i][j], 0, 0, 0);
  }
  int rsub = (lane >> 4) * 4;
#pragma unroll
  for (int i = 0; i < 4; ++i)
#pragma unroll
    for (int j = 0; j < 4; ++j) {
      int col = colBase + wc*64 + j*16 + lr;
      int brow = 128 * (col & 3) + (col >> 2);
      float bv = bias[brow];
#pragma unroll
      for (int rg = 0; rg < 4; ++rg) {
        int row = m0 + wr*64 + i*16 + rsub + rg;
        out[(size_t)row * 512 + col] = acc[i][j][rg] + bv;
      }
    }
}

// ---------------- MFMA bf16: pt[kc][n][d] = sum_{m in chunk} attn[n][m] * hs[m][d] ----------------
#define LDT2 72
__global__ __launch_bounds__(256) void mfma_av(
    const ushort* __restrict__ attnb, const ushort* __restrict__ hsT,
    float* __restrict__ pt, int chunk, int N)
{
  __shared__ ushort As[128][LDT2];
  __shared__ ushort Bs[128][LDT2];
  int tid = threadIdx.x;
  int n0 = blockIdx.x * 128;
  int m0 = blockIdx.y * chunk;
  int lane = tid & 63;
  int wv = tid >> 6, wr = wv >> 1, wc = wv & 1;
  int lr = lane & 15, lk = (lane >> 4) * 8;
  f4v acc[4][4] = {};
  for (int mt = 0; mt < chunk; mt += 64) {
#pragma unroll
    for (int it = 0; it < 4; ++it) {
      int c = it * 256 + tid;
      int r = c >> 3, ch = (c & 7) * 8;
      *(uint4*)&As[r][ch] = *(const uint4*)&attnb[(size_t)(n0 + r) * N + m0 + mt + ch];
      *(uint4*)&Bs[r][ch] = *(const uint4*)&hsT[(size_t)r * N + m0 + mt + ch];
    }
    __syncthreads();
#pragma unroll
    for (int kc = 0; kc < 2; ++kc) {
      s8v a[4], b[4];
#pragma unroll
      for (int i = 0; i < 4; ++i) {
        a[i] = *(const s8v*)&As[wr*64 + i*16 + lr][kc*32 + lk];
        b[i] = *(const s8v*)&Bs[wc*64 + i*16 + lr][kc*32 + lk];
      }
#pragma unroll
      for (int i = 0; i < 4; ++i)
#pragma unroll
        for (int j = 0; j < 4; ++j)
          acc[i][j] = __builtin_amdgcn_mfma_f32_16x16x32_bf16(a[i], b[j], acc[i][j], 0, 0, 0);
    }
    __syncthreads();
  }
  size_t base = ((size_t)blockIdx.y * N + n0) * DIM;
  int rsub = (lane >> 4) * 4;
#pragma unroll
  for (int i = 0; i < 4; ++i)
#pragma unroll
    for (int j = 0; j < 4; ++j) {
      int d = wc*64 + j*16 + lr;
#pragma unroll
      for (int rg = 0; rg < 4; ++rg) {
        int nn = wr*64 + i*16 + rsub + rg;
        pt[base + (size_t)nn * DIM + d] = acc[i][j][rg];
      }
    }
}

// ---------------- row abs-sum over bf16 matrix ----------------
__global__ void row_reduce_abs_bf16(const ushort* __restrict__ W, int ld, int M,
                                    float* __restrict__ out, float eps) {
  int n = blockIdx.x;
  const ushort* row = W + (size_t)n * ld;
  float s = 0;
  for (int m = threadIdx.x * 8; m < M; m += 256 * 8) {
    uint4 v = *(const uint4*)&row[m];
    unsigned a[4] = {v.x, v.y, v.z, v.w};
#pragma unroll
    for (int q = 0; q < 4; ++q) {
      s += __int_as_float((int)((a[q] & 0x7FFFu) << 16));
      s += __int_as_float((int)(a[q] & 0x7FFF0000u));
    }
  }
  __shared__ float red[256];
  red[threadIdx.x] = s; __syncthreads();
  for (int k = 128; k > 0; k >>= 1) {
    if (threadIdx.x < k) red[threadIdx.x] += red[threadIdx.x + k];
    __syncthreads();
  }
  if (threadIdx.x == 0) out[n] = fmaxf(red[0], eps);
}

// ---------------- row mean (fp32) ----------------
__global__ void row_mean(const float* __restrict__ W, int ld, int M,
                         float* __restrict__ out, float inv) {
  int n = blockIdx.x;
  const float* row = W + (size_t)n * ld;
  float s = 0;
  for (int m = threadIdx.x; m < M; m += 256) s += row[m];
  __shared__ float red[256];
  red[threadIdx.x] = s; __syncthreads();
  for (int k = 128; k > 0; k >>= 1) {
    if (threadIdx.x < k) red[threadIdx.x] += red[threadIdx.x + k];
    __syncthreads();
  }
  if (threadIdx.x == 0) out[n] = red[0] * inv;
}

// ---------------- column mean, 2-stage ----------------
__global__ void colmean_part(const float* __restrict__ W, int ld, int rows_per,
                             float* __restrict__ part, int M) {
  int m = blockIdx.x * blockDim.x + threadIdx.x;
  int n0 = blockIdx.y * rows_per;
  float s = 0;
  for (int n = 0; n < rows_per; ++n) s += W[(size_t)(n0 + n) * ld + m];
  part[(size_t)blockIdx.y * M + m] = s;
}
__global__ void colmean_fin(const float* __restrict__ part, int M, int nparts,
                            float* __restrict__ out, float inv) {
  int m = blockIdx.x * blockDim.x + threadIdx.x;
  float s = 0;
  for (int k = 0; k < nparts; ++k) s += part[(size_t)k * M + m];
  out[m] = s * inv;
}

// xs[n][d] += (sum_kc pt[kc][n][d]) / denom[n]
__global__ void axpy_reduce(const float* __restrict__ pt, const float* __restrict__ denom,
                            float* __restrict__ xs, int total) {
  int i = blockIdx.x * blockDim.x + threadIdx.x;
  if (i >= total) return;
  float s = 0;
#pragma unroll
  for (int k = 0; k < 8; ++k) s += pt[(size_t)k * total + i];
  xs[i] += s / denom[i >> 7];
}

__global__ void add_vec(const float* __restrict__ a, const float* __restrict__ b,
                        float* __restrict__ o, int n) {
  int i = blockIdx.x * blockDim.x + threadIdx.x;
  if (i < n) o[i] = a[i] + b[i];
}

// ---------------- bidirectional LSTM v10 (frozen best: ~2284 us) ----------------
#define REP8(X) X(0) X(1) X(2) X(3) X(4) X(5) X(6) X(7)

__global__ __launch_bounds__(512, 2) void lstm_kernel(
    const float* __restrict__ Whh,   // [2][512][128] fp32
    const float* __restrict__ Wxp,   // [2][M][512]  gate-interleaved: col 4u+g
    float* __restrict__ xs_rnn,      // [M][256]
    int M)
{
  int dir = blockIdx.x;
  int tid = threadIdx.x;
  int w = tid >> 6, lane = tid & 63;
  int u  = w * 16 + (lane >> 2);
  int gp = (lane >> 1) & 1;          // 0={i,f} 1={g,o}
  int kh = lane & 1;
  int row0 = gp ? (256 + u) : u;
  const float* base = Whh + (size_t)dir * 512 * DIM;
  const float4* w0p = (const float4*)(base + (size_t)row0 * DIM + kh * 64);
  const float4* w1p = (const float4*)(base + (size_t)(row0 + 128) * DIM + kh * 64);

#define DECLW(r) uint4 wA##r, wB##r;
  REP8(DECLW)
#define LOADW(r) { \
    float4 x = w0p[2*(r)], y = w0p[2*(r)+1]; \
    wA##r = make_uint4(pk2h(x.x,x.y), pk2h(x.z,x.w), pk2h(y.x,y.y), pk2h(y.z,y.w)); \
    x = w1p[2*(r)]; y = w1p[2*(r)+1]; \
    wB##r = make_uint4(pk2h(x.x,x.y), pk2h(x.z,x.w), pk2h(y.x,y.y), pk2h(y.z,y.w)); }
  REP8(LOADW)

  __shared__ __align__(16) _Float16 hbuf[2][DIM];
  if (tid < DIM) hbuf[0][tid] = (_Float16)0.f;
  float c = 0.f;
  __syncthreads();

  const float* WxD = Wxp + (size_t)dir * M * 512;
  int wxcol = 4 * u + 2 * gp;
  int t0 = dir ? (M - 1) : 0;
  float2 wx = *(const float2*)&WxD[(size_t)t0 * 512 + wxcol];
  for (int s = 0; s < M; ++s) {
    int t = dir ? (M - 1 - s) : s;
    float2 wxn = make_float2(0.f, 0.f);
    if (s + 1 < M) {
      int tn = dir ? (M - 2 - s) : (s + 1);
      wxn = *(const float2*)&WxD[(size_t)tn * 512 + wxcol];
    }
    int cur = s & 1;
    const uint4* hb = (const uint4*)(hbuf[cur]) + kh * 8;
    float a0 = 0.f, a1 = 0.f;
#define DOTW(r) { uint4 hv = hb[r]; a0 = dot8u(wA##r, hv, a0); a1 = dot8u(wB##r, hv, a1); }
    REP8(DOTW)
    float z0 = dpp_xadd<0xB1>(a0) + wx.x;
    float z1 = dpp_xadd<0xB1>(a1) + wx.y;
    float av0 = gp ? tanh_fast(z0) : sigm_fast(z0);
    float av1 = sigm_fast(z1);
    float gv = dpp_movf<0x102>(av0);
    float ov = dpp_movf<0x102>(av1);
    if ((lane & 3) == 0) {
      c = av1 * c + av0 * gv;
      float hv = ov * tanh_fast(c);
      hbuf[cur ^ 1][u] = (_Float16)hv;
      xs_rnn[(size_t)t * (2 * DIM) + dir * DIM + u] = fmaxf(hv, 0.f);
    }
    wx = wxn;
    __syncthreads();
  }
#undef DOTW
#undef LOADW
#undef DECLW
#undef REP8
}

// ---------------- weighted mean pooling, 2-stage (multi-block) ----------------
__global__ void pool_part(const float* __restrict__ mat, const float* __restrict__ wv,
                          int chunk, float* __restrict__ part) {
  int t = threadIdx.x; int g = t >> 7, d = t & 127;
  int r0 = blockIdx.x * chunk;
  float acc = 0;
  for (int r = g; r < chunk; r += 8) acc += wv[r0 + r] * mat[(size_t)(r0 + r) * DIM + d];
  __shared__ float red[1024];
  red[t] = acc; __syncthreads();
  if (g == 0) {
    float s = acc;
#pragma unroll
    for (int k = 1; k < 8; ++k) s += red[k * 128 + d];
    part[(size_t)blockIdx.x * DIM + d] = s;
  }
}
__global__ void pool_fin(const float* __restrict__ part, int nparts,
                         float* __restrict__ out, float inv) {
  int d = threadIdx.x;
  float s = 0;
  for (int k = 0; k < nparts; ++k) s += part[(size_t)k * DIM + d];
  out[d] = s * inv;
}

// ---------------- output MLP (1024 thr, 4-way k-split per neuron) ----------------
__global__ void mlp_kernel(const float* __restrict__ cvec, const float* __restrict__ pvec,
                           const float* __restrict__ Wo, const float* __restrict__ bo,
                           const float* __restrict__ Wi, const float* __restrict__ bi,
                           float* __restrict__ out) {
  __shared__ float buf0[256], buf1[256];
  __shared__ float red[1024];
  int t = threadIdx.x;
  int nr = t >> 2, part = t & 3;       // neuron, k-part (64 elems each)
  if (t < 128) buf0[t] = cvec[t];
  else if (t < 256) buf0[t] = pvec[t - 128];
  __syncthreads();
  {
    const float* W = Wo + (size_t)nr * 256 + part * 64;
    const float* x = buf0 + part * 64;
    float s = 0;
    for (int v = 0; v < 64; ++v) s += W[v] * x[v];
    red[t] = s; __syncthreads();
    if (part == 0) buf1[nr] = fmaxf(red[t] + red[t+1] + red[t+2] + red[t+3] + bo[nr], 0.f);
  }
  __syncthreads();
  {
    const float* W = Wo + 256 * 256 + (size_t)nr * 256 + part * 64;
    const float* x = buf1 + part * 64;
    float s = 0;
    for (int v = 0; v < 64; ++v) s += W[v] * x[v];
    red[t] = s; __syncthreads();
    if (part == 0) buf0[nr] = fmaxf(red[t] + red[t+1] + red[t+2] + red[t+3] + bo[256 + nr], 0.f);
  }
  __syncthreads();
  if (t < 8) {
    int o = t >> 2, p = t & 3;
    const float* W = Wi + (size_t)o * 256 + p * 64;
    const float* x = buf0 + p * 64;
    float s = 0;
    for (int v = 0; v < 64; ++v) s += W[v] * x[v];
    red[t] = s;
  }
  __syncthreads();
  if (t < 2)
    out[t] = red[4*t] + red[4*t+1] + red[4*t+2] + red[4*t+3] + bi[t];
}

extern "C" void kernel_launch(void* const* d_in, const int* in_sizes, int n_in,
                              void* d_out, int out_size, void* d_ws, size_t ws_size,
                              hipStream_t stream) {
  const int*   fingerprints = (const int*)d_in[0];
  const float* adjacency    = (const float*)d_in[1];
  const int*   words        = (const int*)d_in[2];
  const float* emb_fp       = (const float*)d_in[3];
  const float* emb_word     = (const float*)d_in[4];
  const float* Wg  = (const float*)d_in[5];
  const float* bg  = (const float*)d_in[6];
  const float* Wih = (const float*)d_in[7];
  const float* Whh = (const float*)d_in[8];
  const float* bih = (const float*)d_in[9];
  const float* bhh = (const float*)d_in[10];
  const float* Wc  = (const float*)d_in[11];
  const float* bc  = (const float*)d_in[12];
  const float* Wp  = (const float*)d_in[13];
  const float* bp  = (const float*)d_in[14];
  const float* Wo  = (const float*)d_in[15];
  const float* bo  = (const float*)d_in[16];
  const float* Wi  = (const float*)d_in[17];
  const float* bi  = (const float*)d_in[18];

  const int N = in_sizes[0];
  const int M = in_sizes[2];
  const int LGAT = in_sizes[5] / (DIM * DIM);

  float* out  = (float*)d_out;
  float* attn = out + 2;                 // [N][M] fp32: final `weights`
  ushort* attnb = (ushort*)attn;         // bf16 scratch during GAT

  float* ws = (float*)d_ws;
  size_t off = 0;
  auto alloc = [&](size_t nf) { float* p = ws + off; off += (nf + 3) & ~(size_t)3; return p; };
  float* xs     = alloc((size_t)N * DIM);
  float* wvb    = alloc((size_t)M * DIM);
  float* denom  = alloc(N);
  float* pt     = alloc((size_t)8 * N * DIM);    // K-split partials; aliased as Wx
  float* Wx     = pt;                            // [2][M][512] gate-interleaved
  float* xs_rnn = alloc((size_t)M * 2 * DIM);
  float* hp     = alloc((size_t)M * DIM);
  float* hmat   = alloc((size_t)N * DIM);
  float* bsum   = alloc(1024);
  float* wcomp  = alloc(N);
  float* wprot  = alloc(M);
  float* cvec   = alloc(DIM);
  float* pvec   = alloc(DIM);
  float* cpart  = alloc((size_t)32 * M);
  float* ppart  = alloc((size_t)16 * DIM);
  ushort* hs_b  = (ushort*)alloc((size_t)N * DIM / 2);   // hs bf16
  ushort* hsT_b = (ushort*)alloc((size_t)N * DIM / 2);   // hs^T bf16 [128][N]
  _Float16* wvb_h  = (_Float16*)alloc((size_t)M * DIM / 2);
  _Float16* wih_h  = (_Float16*)alloc((size_t)2 * 512 * DIM / 2);
  _Float16* hmat_h = (_Float16*)alloc((size_t)N * DIM / 2);
  _Float16* hp_h   = (_Float16*)alloc((size_t)M * DIM / 2);
  (void)ws_size; (void)n_in; (void)out_size;

  // ---- embeddings ----
  gather_rows<<<(N * 32 + 255) / 256, 256, 0, stream>>>(emb_fp, fingerprints, xs, N);
  gather_rows_wv<<<(M * 32 + 255) / 256, 256, 0, stream>>>(emb_word, words, wvb, wvb_h, M);

  // ---- GAT layers (bf16 MFMA inner loop; hs produced directly in bf16) ----
  for (int l = 0; l < LGAT; ++l) {
    gemm_nt<true, 1><<<dim3(DIM / 64, N / 64), 256, 0, stream>>>(
        xs, Wg + (size_t)l * DIM * DIM, nullptr, hs_b, nullptr, DIM, DIM, bg + l * DIM);
    tr_bf16<<<(N * DIM) / 256, 256, 0, stream>>>(hs_b, hsT_b, N);
    mfma_nt_adj<<<dim3(N / 128, N / 128), 256, 0, stream>>>(
        hs_b, hs_b, attnb, N, adjacency, N);
    row_reduce_abs_bf16<<<N, 256, 0, stream>>>(attnb, N, N, denom, 1e-12f);
    mfma_av<<<dim3(N / 128, 8), 256, 0, stream>>>(attnb, hsT_b, pt, N / 8, N);
    axpy_reduce<<<(N * DIM) / 256, 256, 0, stream>>>(pt, denom, xs, N * DIM);
  }

  // ---- LSTM precompute (f16 MFMA Wx) + run ----
  add_vec<<<4, 256, 0, stream>>>(bih, bhh, bsum, 1024);
  conv_f16<<<(2 * 512 * DIM / 4 + 255) / 256, 256, 0, stream>>>(Wih, wih_h, 2 * 512 * DIM / 4);
  for (int d = 0; d < 2; ++d) {
    mfma_wx<<<dim3(512 / 128, M / 128), 256, 0, stream>>>(
        wvb_h, wih_h + (size_t)d * 512 * DIM, bsum + d * 512, Wx + (size_t)d * M * 512);
  }
  lstm_kernel<<<2, 512, 0, stream>>>(Whh, Wx, xs_rnn, M);

  // ---- cross-attention pooling (f16 copies fused into GEMM epilogues) ----
  gemm_nt<true, 2><<<dim3(DIM / 64, M / 64), 256, 0, stream>>>(
      xs_rnn, Wp, hp, nullptr, hp_h, DIM, 2 * DIM, bp);
  gemm_nt<true, 2><<<dim3(DIM / 64, N / 64), 256, 0, stream>>>(
      xs, Wc, hmat, nullptr, hmat_h, DIM, DIM, bc);
  mfma_nt_f32<<<dim3(M / 128, N / 128), 256, 0, stream>>>(hmat_h, hp_h, attn, M);
  row_mean<<<N, 256, 0, stream>>>(attn, M, M, wcomp, 1.f / (float)M);
  colmean_part<<<dim3(M / 256, 32), 256, 0, stream>>>(attn, M, N / 32, cpart, M);
  colmean_fin<<<M / 256, 256, 0, stream>>>(cpart, M, 32, wprot, 1.f / (float)N);
  pool_part<<<16, 1024, 0, stream>>>(hmat, wcomp, N / 16, ppart);
  pool_fin<<<1, DIM, 0, stream>>>(ppart, 16, cvec, 1.f / (float)N);
  pool_part<<<16, 1024, 0, stream>>>(hp, wprot, M / 16, ppart);
  pool_fin<<<1, DIM, 0, stream>>>(ppart, 16, pvec, 1.f / (float)M);

  // ---- output MLP ----
  mlp_kernel<<<1, 1024, 0, stream>>>(cvec, pvec, Wo, bo, Wi, bi, out);
}